// Round 11
// baseline (288.321 us; speedup 1.0000x reference)
//
#include <hip/hip_runtime.h>

typedef unsigned short u16;
typedef short short8 __attribute__((ext_vector_type(8)));
typedef float fx4 __attribute__((ext_vector_type(4)));
typedef u16 u16x4 __attribute__((ext_vector_type(4)));
typedef u16 u16x8 __attribute__((ext_vector_type(8)));

// geometry: b=16, n=1024, d_model=512, heads=8, dim_head=64, inner=512
// ws layout (bytes):
//   xb     @ 0          16,777,216  bf16 [16384][512]
//   wqkv   @ 16777216    1,572,864  bf16 [1536][512]  (Wq rows, Wk rows, Wv rows)
//   wob    @ 18350080      524,288  bf16 [512][512]
//   biasb  @ 18874368   16,777,216  bf16 [8][1024][1024]  (premultiplied by log2e)
//   Qb     @ 35651584   16,777,216  bf16 [16][8][1024][64]
//   Kb     @ 52428800   16,777,216  bf16 [16][8][1024][64]
//   Vtb    @ 69206016   16,777,216  bf16 [16][8][64][1024]  (V transposed)
//   Ob     @ 85983232   16,777,216  bf16 [16384][512]
// total ~102.8 MB

__device__ __forceinline__ u16 f2bf(float f) {
  union { float f; unsigned u; } v; v.f = f;
  unsigned r = (v.u + 0x7fffu + ((v.u >> 16) & 1u)) >> 16;
  return (u16)r;
}
__device__ __forceinline__ float bf2f(u16 u) {
  union { unsigned u; float f; } v; v.u = ((unsigned)u) << 16;
  return v.f;
}
__device__ __forceinline__ void load_lds16(const void* g, void* l) {
  __builtin_amdgcn_global_load_lds((const __attribute__((address_space(1))) void*)g,
                                   (__attribute__((address_space(3))) void*)l, 16, 0, 0);
}
// XOR swizzle for [*][64] bf16 tiles (128 B rows): spreads ds_read_b128 across banks
__device__ __forceinline__ int swz(int row, int colb) {
  return (row << 7) | (colb ^ ((row & 7) << 4));
}

// ---------------------------------------------------------------- convert
__global__ __launch_bounds__(256) void k_convert(
    const float* __restrict__ x, const float* __restrict__ wq, const float* __restrict__ wk,
    const float* __restrict__ wv, const float* __restrict__ wo, const float* __restrict__ bias,
    u16* __restrict__ xb, u16* __restrict__ wqkv, u16* __restrict__ wob, u16* __restrict__ biasb) {
  const int total = 2228224;  // units of 8 elements
  for (int u = blockIdx.x * blockDim.x + threadIdx.x; u < total; u += gridDim.x * blockDim.x) {
    const float* src; u16* dst; int off; float fac = 1.0f;
    if (u < 1048576)      { src = x;    dst = xb;            off = u << 3; }
    else if (u < 1081344) { src = wq;   dst = wqkv;          off = (u - 1048576) << 3; }
    else if (u < 1114112) { src = wk;   dst = wqkv + 262144; off = (u - 1081344) << 3; }
    else if (u < 1146880) { src = wv;   dst = wqkv + 524288; off = (u - 1114112) << 3; }
    else if (u < 1179648) { src = wo;   dst = wob;           off = (u - 1146880) << 3; }
    else { src = bias; dst = biasb; off = (u - 1179648) << 3; fac = 1.44269504089f; }
    float4 a = *(const float4*)(src + off);
    float4 b = *(const float4*)(src + off + 4);
    u16x8 o;
    o[0] = f2bf(a.x * fac); o[1] = f2bf(a.y * fac); o[2] = f2bf(a.z * fac); o[3] = f2bf(a.w * fac);
    o[4] = f2bf(b.x * fac); o[5] = f2bf(b.y * fac); o[6] = f2bf(b.z * fac); o[7] = f2bf(b.w * fac);
    *(u16x8*)(dst + off) = o;
  }
}

// ---------------------------------------------------------------- GEMM core
// C[M,N] = A[M,512] * B[N,512]^T, 128x128 tile, BK=32, 4 waves (2x2), 16x16x32 MFMA.
// Double-buffered staging with counted vmcnt + raw barriers (pattern validated in k_attn r10).
__device__ __forceinline__ void gemm_core(const u16* __restrict__ A, const u16* __restrict__ Bm,
                                          int mt, int nt, int tid, fx4 acc[4][4],
                                          u16* ldsA, u16* ldsB) {
  const int w = tid >> 6, l = tid & 63;
  const int wr = w >> 1, wc = w & 1;
  const int lr = l & 15, kg = (l >> 4) * 8;
  const int seg0 = w * 2, seg1 = w * 2 + 1;
  const int idx0 = seg0 * 512 + l * 8, idx1 = seg1 * 512 + l * 8;
  const int row0 = idx0 >> 5, col0 = idx0 & 31;
  const int row1 = idx1 >> 5, col1 = idx1 & 31;
  const u16* Ab = A  + (size_t)(mt * 128) * 512;
  const u16* Bb = Bm + (size_t)(nt * 128) * 512;

#define GSTAGE(k0, p)                                                              \
  {                                                                                \
    load_lds16(Ab + row0 * 512 + (k0) + col0, (char*)ldsA + (p) * 8192 + seg0 * 1024); \
    load_lds16(Bb + row0 * 512 + (k0) + col0, (char*)ldsB + (p) * 8192 + seg0 * 1024); \
    load_lds16(Ab + row1 * 512 + (k0) + col1, (char*)ldsA + (p) * 8192 + seg1 * 1024); \
    load_lds16(Bb + row1 * 512 + (k0) + col1, (char*)ldsB + (p) * 8192 + seg1 * 1024); \
  }

  GSTAGE(0, 0);  // prologue: tile 0 in flight (4 loads)

  for (int kt = 0; kt < 16; ++kt) {
    const int p = kt & 1;
    __builtin_amdgcn_sched_barrier(0);
    if (kt < 15) {
      GSTAGE((kt + 1) * 32, p ^ 1);  // 8 outstanding
      __builtin_amdgcn_sched_barrier(0);
      asm volatile("s_waitcnt vmcnt(4)" ::: "memory");  // tile-kt's 4 retired
    } else {
      asm volatile("s_waitcnt vmcnt(0)" ::: "memory");
    }
    __builtin_amdgcn_sched_barrier(0);
    __builtin_amdgcn_s_barrier();  // tile-kt visible block-wide

    short8 a[4], b[4];
#pragma unroll
    for (int mi = 0; mi < 4; ++mi)
      a[mi] = *(const short8*)&ldsA[p * 4096 + (wr * 64 + mi * 16 + lr) * 32 + kg];
#pragma unroll
    for (int ni = 0; ni < 4; ++ni)
      b[ni] = *(const short8*)&ldsB[p * 4096 + (wc * 64 + ni * 16 + lr) * 32 + kg];
#pragma unroll
    for (int mi = 0; mi < 4; ++mi)
#pragma unroll
      for (int ni = 0; ni < 4; ++ni)
        acc[mi][ni] = __builtin_amdgcn_mfma_f32_16x16x32_bf16(a[mi], b[ni], acc[mi][ni], 0, 0, 0);
    // trailing barrier: protect buf p from next iteration's GSTAGE(kt+2, p) writes
    __builtin_amdgcn_s_barrier();
  }
#undef GSTAGE
}

// ---------------------------------------------------------------- QKV projection
__global__ __launch_bounds__(256) void k_proj(const u16* __restrict__ xb, const u16* __restrict__ wqkv,
                                              u16* __restrict__ Qb, u16* __restrict__ Kb,
                                              u16* __restrict__ Vtb) {
  __shared__ u16 ldsA[2 * 128 * 32], ldsB[2 * 128 * 32];
  int orig = blockIdx.x;                      // 1536 blocks
  int wgid = (orig & 7) * 192 + (orig >> 3);  // XCD-contiguous chunks
  int mt = wgid / 12, nt = wgid % 12;
  int tid = threadIdx.x;
  fx4 acc[4][4] = {};
  gemm_core(xb, wqkv, mt, nt, tid, acc, ldsA, ldsB);
  const int w = tid >> 6, l = tid & 63, wr = w >> 1, wc = w & 1;
  const int rb = mt * 128 + wr * 64 + ((l >> 4) << 2);
  const int eb = ((nt & 3) << 7) + wc * 64 + (l & 15);
  if (nt < 8) {  // Q (nt 0-3) or K (nt 4-7): [b,h,n,64]
    u16* dst = (nt < 4) ? Qb : Kb;
#pragma unroll
    for (int ni = 0; ni < 4; ++ni) {
      int e = eb + ni * 16, hh = e >> 6, d = e & 63;
#pragma unroll
      for (int mi = 0; mi < 4; ++mi)
#pragma unroll
        for (int j = 0; j < 4; ++j) {
          int r = rb + mi * 16 + j, bb = r >> 10, nn = r & 1023;
          dst[(((bb << 3) + hh) * 1024 + nn) * 64 + d] = f2bf(acc[mi][ni][j]);
        }
    }
  } else {       // V transposed: [b,h,64,n] — pack 4 consecutive n
#pragma unroll
    for (int ni = 0; ni < 4; ++ni) {
      int e = eb + ni * 16, hh = e >> 6, d = e & 63;
#pragma unroll
      for (int mi = 0; mi < 4; ++mi) {
        int r0 = rb + mi * 16, bb = r0 >> 10, nn = r0 & 1023;
        u16x4 p;
#pragma unroll
        for (int j = 0; j < 4; ++j) p[j] = f2bf(acc[mi][ni][j]);
        *(u16x4*)&Vtb[(((bb << 3) + hh) * 64 + d) * 1024 + nn] = p;
      }
    }
  }
}

// ---------------------------------------------------------------- flash attention
// block = (b, h, q-tile of 64); 4 waves x 16 q-rows; KBLK=64; head pinned to XCD.
// Double-buffered K/V staging with counted vmcnt + raw barriers;
// bias pre-scaled by log2e, softmax in exp2 domain (bare v_exp_f32).
__global__ __launch_bounds__(256) void k_attn(const u16* __restrict__ Qb, const u16* __restrict__ Kb,
                                              const u16* __restrict__ Vtb, const u16* __restrict__ biasb,
                                              u16* __restrict__ Ob) {
  __shared__ u16 ldsK[2][64 * 64], ldsV[2][64 * 64];
  __shared__ u16 ldsP[4][16 * 64];
  int orig = blockIdx.x;                      // 2048 blocks
  int wgid = (orig & 7) * 256 + (orig >> 3);  // XCD x owns head x
  int h = wgid >> 8, bb = (wgid >> 4) & 15, qt = wgid & 15;
  const int tid = threadIdx.x, w = tid >> 6, l = tid & 63;
  const int lr = l & 15, g = l >> 4;
  const int q0 = qt * 64;
  const u16*  Qbh = Qb + (size_t)((bb * 8 + h) * 1024) * 64;
  const char* Kc  = (const char*)(Kb  + (size_t)((bb * 8 + h) * 1024) * 64);
  const char* Vc  = (const char*)(Vtb + (size_t)((bb * 8 + h) * 64) * 1024);
  // bias element [h][q0+w*16+g*4+j][kt*64+ct*16+lr], per-thread base:
  const u16* Bt = biasb + ((size_t)h << 20) + (size_t)(q0 + w * 16 + g * 4) * 1024 + lr;
  // Q fragments in registers (A-operand: row = l&15, k = 8*(l>>4)+t)
  const int qrow = q0 + w * 16 + lr;
  short8 qf0 = *(const short8*)&Qbh[qrow * 64 + g * 8];
  short8 qf1 = *(const short8*)&Qbh[qrow * 64 + 32 + g * 8];
  const float SC2 = 0.125f * 1.44269504089f;  // scale * log2e (bias already in log2 domain)
  float m_r[4], l_r[4];
  fx4 acc_o[4] = {};
#pragma unroll
  for (int j = 0; j < 4; ++j) { m_r[j] = -1e30f; l_r[j] = 0.f; }

  // staging: 2 segs/wave for K and V (4 global_load_lds per wave per tile)
  const int segb0 = (w * 2) * 1024, segb1 = (w * 2 + 1) * 1024;
  int o0 = segb0 + l * 16, o1 = segb1 + l * 16;
  int bs0 = o0 ^ (((o0 >> 7) & 7) << 4), bs1 = o1 ^ (((o1 >> 7) & 7) << 4);
  int row0 = bs0 >> 7, colb0 = bs0 & 127;
  int row1 = bs1 >> 7, colb1 = bs1 & 127;

#define STAGE(kt, p)                                                                 \
  {                                                                                  \
    load_lds16(Kc + (size_t)((kt) * 64 + row0) * 128 + colb0, (char*)ldsK[p] + segb0); \
    load_lds16(Vc + (size_t)row0 * 2048 + (kt) * 128 + colb0, (char*)ldsV[p] + segb0); \
    load_lds16(Kc + (size_t)((kt) * 64 + row1) * 128 + colb1, (char*)ldsK[p] + segb1); \
    load_lds16(Vc + (size_t)row1 * 2048 + (kt) * 128 + colb1, (char*)ldsV[p] + segb1); \
  }

  STAGE(0, 0);  // prologue: tile 0 in flight

  for (int kt = 0; kt < 16; ++kt) {
    const int p = kt & 1;
    // bias(kt) -> registers (issued BEFORE next-tile staging so vmcnt(4) covers it)
    u16 br[16];
#pragma unroll
    for (int ct = 0; ct < 4; ++ct)
#pragma unroll
      for (int j = 0; j < 4; ++j)
        br[ct * 4 + j] = Bt[(size_t)j * 1024 + kt * 64 + ct * 16];
    __builtin_amdgcn_sched_barrier(0);
    if (kt < 15) {
      STAGE(kt + 1, p ^ 1);
      __builtin_amdgcn_sched_barrier(0);
      asm volatile("s_waitcnt vmcnt(4)" ::: "memory");  // tile-kt staging + bias(kt) done
    } else {
      asm volatile("s_waitcnt vmcnt(0)" ::: "memory");
    }
    __builtin_amdgcn_sched_barrier(0);
    __builtin_amdgcn_s_barrier();   // all waves' tile-kt portions landed

    // S = Q K^T  (D-layout: col=kv=lr, row=q=g*4+j)
    fx4 s[4];
#pragma unroll
    for (int ct = 0; ct < 4; ++ct) {
      short8 kf0 = *(const short8*)((char*)ldsK[p] + swz(ct * 16 + lr, g * 16));
      short8 kf1 = *(const short8*)((char*)ldsK[p] + swz(ct * 16 + lr, 64 + g * 16));
      fx4 t = {};
      t = __builtin_amdgcn_mfma_f32_16x16x32_bf16(qf0, kf0, t, 0, 0, 0);
      t = __builtin_amdgcn_mfma_f32_16x16x32_bf16(qf1, kf1, t, 0, 0, 0);
      s[ct] = t;
    }
    // scale + bias (log2 domain, from registers)
#pragma unroll
    for (int ct = 0; ct < 4; ++ct)
#pragma unroll
      for (int j = 0; j < 4; ++j)
        s[ct][j] = s[ct][j] * SC2 + bf2f(br[ct * 4 + j]);
    // online softmax, exp2 domain (row lives across the 16 lanes of this quarter-wave)
#pragma unroll
    for (int j = 0; j < 4; ++j) {
      float tm = fmaxf(fmaxf(s[0][j], s[1][j]), fmaxf(s[2][j], s[3][j]));
#pragma unroll
      for (int d = 1; d < 16; d <<= 1) tm = fmaxf(tm, __shfl_xor(tm, d));
      float mn = fmaxf(m_r[j], tm);
      float corr = exp2f(m_r[j] - mn);
      m_r[j] = mn;
      float rs = 0.f;
#pragma unroll
      for (int ct = 0; ct < 4; ++ct) { float p2 = exp2f(s[ct][j] - mn); s[ct][j] = p2; rs += p2; }
#pragma unroll
      for (int d = 1; d < 16; d <<= 1) rs += __shfl_xor(rs, d);
      l_r[j] = l_r[j] * corr + rs;
#pragma unroll
      for (int dt = 0; dt < 4; ++dt) acc_o[dt][j] *= corr;
    }
    // P -> per-wave LDS region (same-wave in-order LDS: no block barrier needed)
    char* Pw = (char*)ldsP[w];
#pragma unroll
    for (int ct = 0; ct < 4; ++ct)
#pragma unroll
      for (int j = 0; j < 4; ++j)
        *(u16*)(Pw + swz(g * 4 + j, (ct * 16 + lr) * 2)) = f2bf(s[ct][j]);
    // O += P V  (A = P: row=q=lr, k=kv; B = V from Vt rows: col=dout=lr)
    short8 pf0 = *(const short8*)(Pw + swz(lr, g * 16));
    short8 pf1 = *(const short8*)(Pw + swz(lr, 64 + g * 16));
#pragma unroll
    for (int dt = 0; dt < 4; ++dt) {
      short8 vf0 = *(const short8*)((char*)ldsV[p] + swz(dt * 16 + lr, g * 16));
      short8 vf1 = *(const short8*)((char*)ldsV[p] + swz(dt * 16 + lr, 64 + g * 16));
      acc_o[dt] = __builtin_amdgcn_mfma_f32_16x16x32_bf16(pf0, vf0, acc_o[dt], 0, 0, 0);
      acc_o[dt] = __builtin_amdgcn_mfma_f32_16x16x32_bf16(pf1, vf1, acc_o[dt], 0, 0, 0);
    }
    // trailing barrier: protect buf p from next iteration's STAGE(kt+2, p) writes
    __builtin_amdgcn_s_barrier();
  }
#undef STAGE
  // epilogue: normalize and store O[b, n, h*64+d] bf16
#pragma unroll
  for (int j = 0; j < 4; ++j) {
    float inv = 1.f / l_r[j];
    int q = q0 + w * 16 + g * 4 + j;
#pragma unroll
    for (int dt = 0; dt < 4; ++dt) {
      int col = h * 64 + dt * 16 + lr;
      Ob[(size_t)(bb * 1024 + q) * 512 + col] = f2bf(acc_o[dt][j] * inv);
    }
  }
}

// ---------------------------------------------------------------- output projection
__global__ __launch_bounds__(256) void k_out(const u16* __restrict__ Ob, const u16* __restrict__ Wob,
                                             const float* __restrict__ bo, float* __restrict__ out) {
  __shared__ u16 ldsA[2 * 128 * 32], ldsB[2 * 128 * 32];
  int orig = blockIdx.x;                     // 512 blocks
  int wgid = (orig & 7) * 64 + (orig >> 3);
  int mt = wgid >> 2, nt = wgid & 3;
  int tid = threadIdx.x;
  fx4 acc[4][4] = {};
  gemm_core(Ob, Wob, mt, nt, tid, acc, ldsA, ldsB);
  const int w = tid >> 6, l = tid & 63, wr = w >> 1, wc = w & 1;
  const int rb = mt * 128 + wr * 64 + ((l >> 4) << 2);
  const int eb = nt * 128 + wc * 64 + (l & 15);
#pragma unroll
  for (int ni = 0; ni < 4; ++ni) {
    int e = eb + ni * 16;
    float bv = bo[e];
#pragma unroll
    for (int mi = 0; mi < 4; ++mi)
#pragma unroll
      for (int j = 0; j < 4; ++j) {
        int r = rb + mi * 16 + j;
        out[(size_t)r * 512 + e] = acc[mi][ni][j] + bv;
      }
  }
}

// ---------------------------------------------------------------- launch
extern "C" void kernel_launch(void* const* d_in, const int* in_sizes, int n_in,
                              void* d_out, int out_size, void* d_ws, size_t ws_size,
                              hipStream_t stream) {
  const float* x    = (const float*)d_in[0];
  const float* wq   = (const float*)d_in[1];
  const float* wk   = (const float*)d_in[2];
  const float* wv   = (const float*)d_in[3];
  const float* bias = (const float*)d_in[4];
  const float* wo   = (const float*)d_in[5];
  const float* bo   = (const float*)d_in[6];
  float* out = (float*)d_out;
  char* ws = (char*)d_ws;
  u16* xb    = (u16*)(ws + 0);
  u16* wqkv  = (u16*)(ws + 16777216);
  u16* wob   = (u16*)(ws + 18350080);
  u16* biasb = (u16*)(ws + 18874368);
  u16* Qb    = (u16*)(ws + 35651584);
  u16* Kb    = (u16*)(ws + 52428800);
  u16* Vtb   = (u16*)(ws + 69206016);
  u16* Ob    = (u16*)(ws + 85983232);

  hipLaunchKernelGGL(k_convert, dim3(2048), dim3(256), 0, stream,
                     x, wq, wk, wv, wo, bias, xb, wqkv, wob, biasb);
  hipLaunchKernelGGL(k_proj, dim3(1536), dim3(256), 0, stream, xb, wqkv, Qb, Kb, Vtb);
  hipLaunchKernelGGL(k_attn, dim3(2048), dim3(256), 0, stream, Qb, Kb, Vtb, biasb, Ob);
  hipLaunchKernelGGL(k_out, dim3(512), dim3(256), 0, stream, Ob, wob, bo, out);
}

// Round 12
// 277.425 us; speedup vs baseline: 1.0393x; 1.0393x over previous
//
#include <hip/hip_runtime.h>

typedef unsigned short u16;
typedef short short8 __attribute__((ext_vector_type(8)));
typedef float fx4 __attribute__((ext_vector_type(4)));
typedef u16 u16x4 __attribute__((ext_vector_type(4)));
typedef u16 u16x8 __attribute__((ext_vector_type(8)));

// geometry: b=16, n=1024, d_model=512, heads=8, dim_head=64, inner=512
// ws layout (bytes):
//   xb     @ 0          16,777,216  bf16 [16384][512]
//   wqkv   @ 16777216    1,572,864  bf16 [1536][512]  (Wq rows, Wk rows, Wv rows)
//   wob    @ 18350080      524,288  bf16 [512][512]
//   biasb  @ 18874368   16,777,216  bf16 [8][1024][1024]  (premultiplied by log2e)
//   Qb     @ 35651584   16,777,216  bf16 [16][8][1024][64]
//   Kb     @ 52428800   16,777,216  bf16 [16][8][1024][64]
//   Vtb    @ 69206016   16,777,216  bf16 [16][8][64][1024]  (V transposed)
//   Ob     @ 85983232   16,777,216  bf16 [16384][512]
// total ~102.8 MB

__device__ __forceinline__ u16 f2bf(float f) {
  union { float f; unsigned u; } v; v.f = f;
  unsigned r = (v.u + 0x7fffu + ((v.u >> 16) & 1u)) >> 16;
  return (u16)r;
}
__device__ __forceinline__ float bf2f(u16 u) {
  union { unsigned u; float f; } v; v.u = ((unsigned)u) << 16;
  return v.f;
}
__device__ __forceinline__ void load_lds16(const void* g, void* l) {
  __builtin_amdgcn_global_load_lds((const __attribute__((address_space(1))) void*)g,
                                   (__attribute__((address_space(3))) void*)l, 16, 0, 0);
}
// XOR swizzle for [*][64] bf16 tiles (128 B rows): spreads ds_read_b128 across banks
__device__ __forceinline__ int swz(int row, int colb) {
  return (row << 7) | (colb ^ ((row & 7) << 4));
}

// ---------------------------------------------------------------- convert
__global__ __launch_bounds__(256) void k_convert(
    const float* __restrict__ x, const float* __restrict__ wq, const float* __restrict__ wk,
    const float* __restrict__ wv, const float* __restrict__ wo, const float* __restrict__ bias,
    u16* __restrict__ xb, u16* __restrict__ wqkv, u16* __restrict__ wob, u16* __restrict__ biasb) {
  const int total = 2228224;  // units of 8 elements
  for (int u = blockIdx.x * blockDim.x + threadIdx.x; u < total; u += gridDim.x * blockDim.x) {
    const float* src; u16* dst; int off; float fac = 1.0f;
    if (u < 1048576)      { src = x;    dst = xb;            off = u << 3; }
    else if (u < 1081344) { src = wq;   dst = wqkv;          off = (u - 1048576) << 3; }
    else if (u < 1114112) { src = wk;   dst = wqkv + 262144; off = (u - 1081344) << 3; }
    else if (u < 1146880) { src = wv;   dst = wqkv + 524288; off = (u - 1114112) << 3; }
    else if (u < 1179648) { src = wo;   dst = wob;           off = (u - 1146880) << 3; }
    else { src = bias; dst = biasb; off = (u - 1179648) << 3; fac = 1.44269504089f; }
    float4 a = *(const float4*)(src + off);
    float4 b = *(const float4*)(src + off + 4);
    u16x8 o;
    o[0] = f2bf(a.x * fac); o[1] = f2bf(a.y * fac); o[2] = f2bf(a.z * fac); o[3] = f2bf(a.w * fac);
    o[4] = f2bf(b.x * fac); o[5] = f2bf(b.y * fac); o[6] = f2bf(b.z * fac); o[7] = f2bf(b.w * fac);
    *(u16x8*)(dst + off) = o;
  }
}

// ---------------------------------------------------------------- GEMM core
// C[M,N] = A[M,512] * B[N,512]^T, 128x128 tile, BK=32, 4 waves (2x2), 16x16x32 MFMA.
// Double-buffered staging with counted vmcnt + raw barriers (validated r10/r11: ~7 µs net win).
__device__ __forceinline__ void gemm_core(const u16* __restrict__ A, const u16* __restrict__ Bm,
                                          int mt, int nt, int tid, fx4 acc[4][4],
                                          u16* ldsA, u16* ldsB) {
  const int w = tid >> 6, l = tid & 63;
  const int wr = w >> 1, wc = w & 1;
  const int lr = l & 15, kg = (l >> 4) * 8;
  const int seg0 = w * 2, seg1 = w * 2 + 1;
  const int idx0 = seg0 * 512 + l * 8, idx1 = seg1 * 512 + l * 8;
  const int row0 = idx0 >> 5, col0 = idx0 & 31;
  const int row1 = idx1 >> 5, col1 = idx1 & 31;
  const u16* Ab = A  + (size_t)(mt * 128) * 512;
  const u16* Bb = Bm + (size_t)(nt * 128) * 512;

#define GSTAGE(k0, p)                                                              \
  {                                                                                \
    load_lds16(Ab + row0 * 512 + (k0) + col0, (char*)ldsA + (p) * 8192 + seg0 * 1024); \
    load_lds16(Bb + row0 * 512 + (k0) + col0, (char*)ldsB + (p) * 8192 + seg0 * 1024); \
    load_lds16(Ab + row1 * 512 + (k0) + col1, (char*)ldsA + (p) * 8192 + seg1 * 1024); \
    load_lds16(Bb + row1 * 512 + (k0) + col1, (char*)ldsB + (p) * 8192 + seg1 * 1024); \
  }

  GSTAGE(0, 0);  // prologue: tile 0 in flight (4 loads)

  for (int kt = 0; kt < 16; ++kt) {
    const int p = kt & 1;
    __builtin_amdgcn_sched_barrier(0);
    if (kt < 15) {
      GSTAGE((kt + 1) * 32, p ^ 1);  // 8 outstanding
      __builtin_amdgcn_sched_barrier(0);
      asm volatile("s_waitcnt vmcnt(4)" ::: "memory");  // tile-kt's 4 retired
    } else {
      asm volatile("s_waitcnt vmcnt(0)" ::: "memory");
    }
    __builtin_amdgcn_sched_barrier(0);
    __builtin_amdgcn_s_barrier();  // tile-kt visible block-wide

    short8 a[4], b[4];
#pragma unroll
    for (int mi = 0; mi < 4; ++mi)
      a[mi] = *(const short8*)&ldsA[p * 4096 + (wr * 64 + mi * 16 + lr) * 32 + kg];
#pragma unroll
    for (int ni = 0; ni < 4; ++ni)
      b[ni] = *(const short8*)&ldsB[p * 4096 + (wc * 64 + ni * 16 + lr) * 32 + kg];
#pragma unroll
    for (int mi = 0; mi < 4; ++mi)
#pragma unroll
      for (int ni = 0; ni < 4; ++ni)
        acc[mi][ni] = __builtin_amdgcn_mfma_f32_16x16x32_bf16(a[mi], b[ni], acc[mi][ni], 0, 0, 0);
    // trailing barrier: protect buf p from next iteration's GSTAGE(kt+2, p) writes
    __builtin_amdgcn_s_barrier();
  }
#undef GSTAGE
}

// ---------------------------------------------------------------- QKV projection
__global__ __launch_bounds__(256) void k_proj(const u16* __restrict__ xb, const u16* __restrict__ wqkv,
                                              u16* __restrict__ Qb, u16* __restrict__ Kb,
                                              u16* __restrict__ Vtb) {
  __shared__ u16 ldsA[2 * 128 * 32], ldsB[2 * 128 * 32];
  int orig = blockIdx.x;                      // 1536 blocks
  int wgid = (orig & 7) * 192 + (orig >> 3);  // XCD-contiguous chunks
  int mt = wgid / 12, nt = wgid % 12;
  int tid = threadIdx.x;
  fx4 acc[4][4] = {};
  gemm_core(xb, wqkv, mt, nt, tid, acc, ldsA, ldsB);
  const int w = tid >> 6, l = tid & 63, wr = w >> 1, wc = w & 1;
  const int rb = mt * 128 + wr * 64 + ((l >> 4) << 2);
  const int eb = ((nt & 3) << 7) + wc * 64 + (l & 15);
  if (nt < 8) {  // Q (nt 0-3) or K (nt 4-7): [b,h,n,64]
    u16* dst = (nt < 4) ? Qb : Kb;
#pragma unroll
    for (int ni = 0; ni < 4; ++ni) {
      int e = eb + ni * 16, hh = e >> 6, d = e & 63;
#pragma unroll
      for (int mi = 0; mi < 4; ++mi)
#pragma unroll
        for (int j = 0; j < 4; ++j) {
          int r = rb + mi * 16 + j, bb = r >> 10, nn = r & 1023;
          dst[(((bb << 3) + hh) * 1024 + nn) * 64 + d] = f2bf(acc[mi][ni][j]);
        }
    }
  } else {       // V transposed: [b,h,64,n] — pack 4 consecutive n
#pragma unroll
    for (int ni = 0; ni < 4; ++ni) {
      int e = eb + ni * 16, hh = e >> 6, d = e & 63;
#pragma unroll
      for (int mi = 0; mi < 4; ++mi) {
        int r0 = rb + mi * 16, bb = r0 >> 10, nn = r0 & 1023;
        u16x4 p;
#pragma unroll
        for (int j = 0; j < 4; ++j) p[j] = f2bf(acc[mi][ni][j]);
        *(u16x4*)&Vtb[(((bb << 3) + hh) * 64 + d) * 1024 + nn] = p;
      }
    }
  }
}

// ---------------------------------------------------------------- flash attention
// block = (b, h, q-tile of 64); 4 waves x 16 q-rows; KBLK=64; head pinned to XCD.
// Double-buffered K/V staging with counted vmcnt + raw barriers;
// bias pre-scaled by log2e, softmax via __builtin_amdgcn_exp2f (bare v_exp_f32).
__global__ __launch_bounds__(256) void k_attn(const u16* __restrict__ Qb, const u16* __restrict__ Kb,
                                              const u16* __restrict__ Vtb, const u16* __restrict__ biasb,
                                              u16* __restrict__ Ob) {
  __shared__ u16 ldsK[2][64 * 64], ldsV[2][64 * 64];
  __shared__ u16 ldsP[4][16 * 64];
  int orig = blockIdx.x;                      // 2048 blocks
  int wgid = (orig & 7) * 256 + (orig >> 3);  // XCD x owns head x
  int h = wgid >> 8, bb = (wgid >> 4) & 15, qt = wgid & 15;
  const int tid = threadIdx.x, w = tid >> 6, l = tid & 63;
  const int lr = l & 15, g = l >> 4;
  const int q0 = qt * 64;
  const u16*  Qbh = Qb + (size_t)((bb * 8 + h) * 1024) * 64;
  const char* Kc  = (const char*)(Kb  + (size_t)((bb * 8 + h) * 1024) * 64);
  const char* Vc  = (const char*)(Vtb + (size_t)((bb * 8 + h) * 64) * 1024);
  // bias element [h][q0+w*16+g*4+j][kt*64+ct*16+lr], per-thread base:
  const u16* Bt = biasb + ((size_t)h << 20) + (size_t)(q0 + w * 16 + g * 4) * 1024 + lr;
  // Q fragments in registers (A-operand: row = l&15, k = 8*(l>>4)+t)
  const int qrow = q0 + w * 16 + lr;
  short8 qf0 = *(const short8*)&Qbh[qrow * 64 + g * 8];
  short8 qf1 = *(const short8*)&Qbh[qrow * 64 + 32 + g * 8];
  const float SC2 = 0.125f * 1.44269504089f;  // scale * log2e (bias already in log2 domain)
  float m_r[4], l_r[4];
  fx4 acc_o[4] = {};
#pragma unroll
  for (int j = 0; j < 4; ++j) { m_r[j] = -1e30f; l_r[j] = 0.f; }

  // staging: 2 segs/wave for K and V (4 global_load_lds per wave per tile)
  const int segb0 = (w * 2) * 1024, segb1 = (w * 2 + 1) * 1024;
  int o0 = segb0 + l * 16, o1 = segb1 + l * 16;
  int bs0 = o0 ^ (((o0 >> 7) & 7) << 4), bs1 = o1 ^ (((o1 >> 7) & 7) << 4);
  int row0 = bs0 >> 7, colb0 = bs0 & 127;
  int row1 = bs1 >> 7, colb1 = bs1 & 127;

#define STAGE(kt, p)                                                                 \
  {                                                                                  \
    load_lds16(Kc + (size_t)((kt) * 64 + row0) * 128 + colb0, (char*)ldsK[p] + segb0); \
    load_lds16(Vc + (size_t)row0 * 2048 + (kt) * 128 + colb0, (char*)ldsV[p] + segb0); \
    load_lds16(Kc + (size_t)((kt) * 64 + row1) * 128 + colb1, (char*)ldsK[p] + segb1); \
    load_lds16(Vc + (size_t)row1 * 2048 + (kt) * 128 + colb1, (char*)ldsV[p] + segb1); \
  }

  STAGE(0, 0);  // prologue: tile 0 in flight

  for (int kt = 0; kt < 16; ++kt) {
    const int p = kt & 1;
    // bias(kt) -> registers (issued BEFORE next-tile staging so vmcnt(4) covers it)
    u16 br[16];
#pragma unroll
    for (int ct = 0; ct < 4; ++ct)
#pragma unroll
      for (int j = 0; j < 4; ++j)
        br[ct * 4 + j] = Bt[(size_t)j * 1024 + kt * 64 + ct * 16];
    __builtin_amdgcn_sched_barrier(0);
    if (kt < 15) {
      STAGE(kt + 1, p ^ 1);
      __builtin_amdgcn_sched_barrier(0);
      asm volatile("s_waitcnt vmcnt(4)" ::: "memory");  // tile-kt staging + bias(kt) done
    } else {
      asm volatile("s_waitcnt vmcnt(0)" ::: "memory");
    }
    __builtin_amdgcn_sched_barrier(0);
    __builtin_amdgcn_s_barrier();   // all waves' tile-kt portions landed

    // S = Q K^T  (D-layout: col=kv=lr, row=q=g*4+j)
    fx4 s[4];
#pragma unroll
    for (int ct = 0; ct < 4; ++ct) {
      short8 kf0 = *(const short8*)((char*)ldsK[p] + swz(ct * 16 + lr, g * 16));
      short8 kf1 = *(const short8*)((char*)ldsK[p] + swz(ct * 16 + lr, 64 + g * 16));
      fx4 t = {};
      t = __builtin_amdgcn_mfma_f32_16x16x32_bf16(qf0, kf0, t, 0, 0, 0);
      t = __builtin_amdgcn_mfma_f32_16x16x32_bf16(qf1, kf1, t, 0, 0, 0);
      s[ct] = t;
    }
    // scale + bias (log2 domain, from registers)
#pragma unroll
    for (int ct = 0; ct < 4; ++ct)
#pragma unroll
      for (int j = 0; j < 4; ++j)
        s[ct][j] = s[ct][j] * SC2 + bf2f(br[ct * 4 + j]);
    // online softmax, exp2 domain via bare v_exp_f32
#pragma unroll
    for (int j = 0; j < 4; ++j) {
      float tm = fmaxf(fmaxf(s[0][j], s[1][j]), fmaxf(s[2][j], s[3][j]));
#pragma unroll
      for (int d = 1; d < 16; d <<= 1) tm = fmaxf(tm, __shfl_xor(tm, d));
      float mn = fmaxf(m_r[j], tm);
      float corr = __builtin_amdgcn_exp2f(m_r[j] - mn);
      m_r[j] = mn;
      float rs = 0.f;
#pragma unroll
      for (int ct = 0; ct < 4; ++ct) {
        float p2 = __builtin_amdgcn_exp2f(s[ct][j] - mn);
        s[ct][j] = p2; rs += p2;
      }
#pragma unroll
      for (int d = 1; d < 16; d <<= 1) rs += __shfl_xor(rs, d);
      l_r[j] = l_r[j] * corr + rs;
#pragma unroll
      for (int dt = 0; dt < 4; ++dt) acc_o[dt][j] *= corr;
    }
    // P -> per-wave LDS region (same-wave in-order LDS: no block barrier needed)
    char* Pw = (char*)ldsP[w];
#pragma unroll
    for (int ct = 0; ct < 4; ++ct)
#pragma unroll
      for (int j = 0; j < 4; ++j)
        *(u16*)(Pw + swz(g * 4 + j, (ct * 16 + lr) * 2)) = f2bf(s[ct][j]);
    // O += P V  (A = P: row=q=lr, k=kv; B = V from Vt rows: col=dout=lr)
    short8 pf0 = *(const short8*)(Pw + swz(lr, g * 16));
    short8 pf1 = *(const short8*)(Pw + swz(lr, 64 + g * 16));
#pragma unroll
    for (int dt = 0; dt < 4; ++dt) {
      short8 vf0 = *(const short8*)((char*)ldsV[p] + swz(dt * 16 + lr, g * 16));
      short8 vf1 = *(const short8*)((char*)ldsV[p] + swz(dt * 16 + lr, 64 + g * 16));
      acc_o[dt] = __builtin_amdgcn_mfma_f32_16x16x32_bf16(pf0, vf0, acc_o[dt], 0, 0, 0);
      acc_o[dt] = __builtin_amdgcn_mfma_f32_16x16x32_bf16(pf1, vf1, acc_o[dt], 0, 0, 0);
    }
    // trailing barrier: protect buf p from next iteration's STAGE(kt+2, p) writes
    __builtin_amdgcn_s_barrier();
  }
#undef STAGE
  // epilogue: normalize and store O[b, n, h*64+d] bf16
#pragma unroll
  for (int j = 0; j < 4; ++j) {
    float inv = 1.f / l_r[j];
    int q = q0 + w * 16 + g * 4 + j;
#pragma unroll
    for (int dt = 0; dt < 4; ++dt) {
      int col = h * 64 + dt * 16 + lr;
      Ob[(size_t)(bb * 1024 + q) * 512 + col] = f2bf(acc_o[dt][j] * inv);
    }
  }
}

// ---------------------------------------------------------------- output projection
__global__ __launch_bounds__(256) void k_out(const u16* __restrict__ Ob, const u16* __restrict__ Wob,
                                             const float* __restrict__ bo, float* __restrict__ out) {
  __shared__ u16 ldsA[2 * 128 * 32], ldsB[2 * 128 * 32];
  int orig = blockIdx.x;                     // 512 blocks
  int wgid = (orig & 7) * 64 + (orig >> 3);
  int mt = wgid >> 2, nt = wgid & 3;
  int tid = threadIdx.x;
  fx4 acc[4][4] = {};
  gemm_core(Ob, Wob, mt, nt, tid, acc, ldsA, ldsB);
  const int w = tid >> 6, l = tid & 63, wr = w >> 1, wc = w & 1;
  const int rb = mt * 128 + wr * 64 + ((l >> 4) << 2);
  const int eb = nt * 128 + wc * 64 + (l & 15);
#pragma unroll
  for (int ni = 0; ni < 4; ++ni) {
    int e = eb + ni * 16;
    float bv = bo[e];
#pragma unroll
    for (int mi = 0; mi < 4; ++mi)
#pragma unroll
      for (int j = 0; j < 4; ++j) {
        int r = rb + mi * 16 + j;
        out[(size_t)r * 512 + e] = acc[mi][ni][j] + bv;
      }
  }
}

// ---------------------------------------------------------------- launch
extern "C" void kernel_launch(void* const* d_in, const int* in_sizes, int n_in,
                              void* d_out, int out_size, void* d_ws, size_t ws_size,
                              hipStream_t stream) {
  const float* x    = (const float*)d_in[0];
  const float* wq   = (const float*)d_in[1];
  const float* wk   = (const float*)d_in[2];
  const float* wv   = (const float*)d_in[3];
  const float* bias = (const float*)d_in[4];
  const float* wo   = (const float*)d_in[5];
  const float* bo   = (const float*)d_in[6];
  float* out = (float*)d_out;
  char* ws = (char*)d_ws;
  u16* xb    = (u16*)(ws + 0);
  u16* wqkv  = (u16*)(ws + 16777216);
  u16* wob   = (u16*)(ws + 18350080);
  u16* biasb = (u16*)(ws + 18874368);
  u16* Qb    = (u16*)(ws + 35651584);
  u16* Kb    = (u16*)(ws + 52428800);
  u16* Vtb   = (u16*)(ws + 69206016);
  u16* Ob    = (u16*)(ws + 85983232);

  hipLaunchKernelGGL(k_convert, dim3(2048), dim3(256), 0, stream,
                     x, wq, wk, wv, wo, bias, xb, wqkv, wob, biasb);
  hipLaunchKernelGGL(k_proj, dim3(1536), dim3(256), 0, stream, xb, wqkv, Qb, Kb, Vtb);
  hipLaunchKernelGGL(k_attn, dim3(2048), dim3(256), 0, stream, Qb, Kb, Vtb, biasb, Ob);
  hipLaunchKernelGGL(k_out, dim3(512), dim3(256), 0, stream, Ob, wob, bo, out);
}